// Round 1
// 203.916 us; speedup vs baseline: 1.0006x; 1.0006x over previous
//
#include <hip/hip_runtime.h>

#define BATCH   65536
#define STEPS   200
#define TCHUNK  8
#define NCHUNK  (STEPS / TCHUNK)   // 25
#define BLK     64                 // one wave per block -> no s_barrier needed at all
#define LSTRIDE 36                 // dwords per lane row: 144 B, float4-aligned

// One SEIR step + stash state as a single ds_write_b128.
// Math is bit-identical to the previous (passing, absmax=16.0) kernel.
__device__ __forceinline__ void step_and_stash(
    float4& x, float A, float B, float C, float invN,
    float* __restrict__ buf, int lane, int tt)
{
    float infl = B * x.x * (x.y + x.z) * invN;
    float ae = A * x.y;
    float ci = C * x.z;
    float d0 = -infl;
    float d1 = infl - ae;
    float d2 = ae - ci;
    float d3 = ci;
    d0 = fminf(fmaxf(d0, -100000.0f), 100000.0f);
    d1 = fminf(fmaxf(d1, -100000.0f), 100000.0f);
    d2 = fminf(fmaxf(d2, -100000.0f), 100000.0f);
    d3 = fminf(fmaxf(d3, -100000.0f), 100000.0f);
    x.x += 0.5f * d0;
    x.y += 0.5f * d1;
    x.z += 0.5f * d2;
    x.w += 0.5f * d3;
    // write banks: 4-bank group = (lane + tt) & 7 -> 8 lanes/group = b128 minimum, free
    *reinterpret_cast<float4*>(&buf[lane * LSTRIDE + tt * 4]) = x;
}

__device__ __forceinline__ void compute_chunk(
    float4& x, float A, float B, float C, float invN,
    float* __restrict__ buf, int lane)
{
    #pragma unroll
    for (int tt = 0; tt < TCHUNK; ++tt)
        step_and_stash(x, A, B, C, invN, buf, lane, tt);
}

// Coalesced flush of one chunk: 8 ds_read_b128 + 8 global_store_dwordx4 per lane.
// Lane group of 8 covers one batch element's 8 consecutive float4 (128 B contiguous):
// each store instruction writes 16 FULL 64B lines.
__device__ __forceinline__ void flush_chunk(
    const float* __restrict__ buf, float4* __restrict__ outf4,
    int base_b, int bbase, int jj, int t0)
{
    float4 f[8];
    #pragma unroll
    for (int k = 0; k < 8; ++k) {
        const int bb = k * 8 + bbase;
        // read banks: 4-bank group = (bb + jj) & 7, uniform over 64 lanes -> minimum, free
        f[k] = *reinterpret_cast<const float4*>(&buf[bb * LSTRIDE + jj * 4]);
    }
    #pragma unroll
    for (int k = 0; k < 8; ++k) {
        const int bb = k * 8 + bbase;
        outf4[(size_t)(base_b + bb) * STEPS + t0 + jj] = f[k];
    }
}

__global__ __launch_bounds__(BLK) void seir_kernel(
    const float* __restrict__ init,
    const float* __restrict__ w,
    float* __restrict__ out)
{
    // Two SEPARATE shared arrays -> provable non-aliasing, so the scheduler can
    // interleave flush reads/stores of one buffer with compute ds_writes of the other.
    __shared__ float ldsA[BLK * LSTRIDE];   // 9216 B
    __shared__ float ldsB[BLK * LSTRIDE];   // 9216 B

    const int lane   = threadIdx.x;          // 0..63
    const int base_b = blockIdx.x * BLK;
    const int b      = base_b + lane;

    // flush geometry: s = k*64+lane -> bb = k*8 + (lane>>3), j = lane&7 (k-invariant)
    const int jj    = lane & 7;
    const int bbase = lane >> 3;

    const float A = w[4];
    const float B = w[5];
    const float C = w[6];
    const float invN = 1.0f / 100000.0f;

    float4 x = reinterpret_cast<const float4*>(init)[b];
    float4* outf4 = reinterpret_cast<float4*>(out);

    // Software pipeline over chunks, NO barriers anywhere:
    //   block = 1 wave, and DS ops within a wave execute in order, so
    //   read(chunk k) -before- write(chunk k+2) is guaranteed by program order.
    //   Global stores of chunk k stay in flight under compute of chunk k+1
    //   (vmcnt never drains to 0 inside the loop).
    compute_chunk(x, A, B, C, invN, ldsA, lane);            // chunk 0 -> A

    // chunks: even -> A, odd -> B. 25 chunks total.
    for (int c = 1; c < NCHUNK; c += 2) {
        // flush chunk c-1 (even, in A), compute chunk c (odd) into B
        flush_chunk(ldsA, outf4, base_b, bbase, jj, (c - 1) * TCHUNK);
        compute_chunk(x, A, B, C, invN, ldsB, lane);
        // flush chunk c (odd, in B), compute chunk c+1 (even) into A
        flush_chunk(ldsB, outf4, base_b, bbase, jj, c * TCHUNK);
        compute_chunk(x, A, B, C, invN, ldsA, lane);
    }
    // final flush: chunk 24 (even) lives in A
    flush_chunk(ldsA, outf4, base_b, bbase, jj, (NCHUNK - 1) * TCHUNK);
}

extern "C" void kernel_launch(void* const* d_in, const int* in_sizes, int n_in,
                              void* d_out, int out_size, void* d_ws, size_t ws_size,
                              hipStream_t stream) {
    const float* init = (const float*)d_in[0];
    const float* w    = (const float*)d_in[1];
    float* out        = (float*)d_out;

    seir_kernel<<<dim3(BATCH / BLK), dim3(BLK), 0, stream>>>(init, w, out);
}